// Round 6
// baseline (363.961 us; speedup 1.0000x reference)
//
#include <hip/hip_runtime.h>
#include <stdint.h>

#define SEQN 16384
#define NBATCH 4

typedef __attribute__((ext_vector_type(8))) __bf16 bf16x8;
typedef __attribute__((ext_vector_type(4))) float f32x4;
typedef __attribute__((ext_vector_type(4))) unsigned int u32x4;

__device__ __forceinline__ unsigned int f2bf(float f) {
  unsigned int x = __builtin_bit_cast(unsigned int, f);
  x = x + 0x7fffu + ((x >> 16) & 1u);
  return x >> 16;
}
__device__ __forceinline__ float bf2f(unsigned int lo) {
  return __builtin_bit_cast(float, lo << 16);
}

__device__ __forceinline__ void gload_lds16(const unsigned short* g, unsigned char* l) {
  __builtin_amdgcn_global_load_lds(
      (const __attribute__((address_space(1))) unsigned int*)g,
      (__attribute__((address_space(3))) unsigned int*)l, 16, 0, 0);
}

// ---------------- g1: QKV projection with fused f32->bf16 conversion -------
// C = cvt_bf16(A_f32) @ Bt^T + bias.  A: [M][512] f32, Bt: [Ncols][512] bf16.
// m97-style 128x128 tile, BK=64, 4 waves (2x2), proven 2-barrier loop.
// B staged via global_load_lds (pre-swizzled source, linear LDS — rule #21).
// A reg-staged: coalesced float4 x2 -> 8 cvts -> ds_write_b128, writing the
// SAME swizzled-content/linear-layout LDS image as R4's gload_lds path, so
// the fragment-read addressing is byte-identical to the proven kernel.
__global__ __launch_bounds__(256, 4)
void gemm_a32(const float* __restrict__ A,
              const unsigned short* __restrict__ Bt,
              const float* __restrict__ bias,
              unsigned short* __restrict__ Cout,
              int Ncols, int K)
{
  __shared__ __align__(16) unsigned char lA[128 * 64 * 2];
  __shared__ __align__(16) unsigned char lB[128 * 64 * 2];
  const int tid = threadIdx.x;
  const int lane = tid & 63;
  const int wid = tid >> 6;
  const int wr = (wid >> 1) * 64;
  const int wc = (wid & 1) * 64;
  const int nbx = Ncols >> 7;
  const int bid = (int)blockIdx.x;
  const int cpx = (int)gridDim.x >> 3;
  const int swz = (bid & 7) * cpx + (bid >> 3);   // XCD-chunked (grid%8==0)
  const int bx = swz % nbx;
  const int by = swz / nbx;
  const long row0 = (long)by << 7;
  const int col0 = bx << 7;

  f32x4 acc[4][4];
#pragma unroll
  for (int i = 0; i < 4; ++i)
#pragma unroll
    for (int j = 0; j < 4; ++j) acc[i][j] = (f32x4)0.0f;

  for (int kt = 0; kt < K; kt += 64) {
    // B: async global->LDS (granule f: row r=f>>3, src chunk (f&7)^(r&7))
#pragma unroll
    for (int i = 0; i < 4; ++i) {
      const int f = i * 256 + tid;
      const int r = f >> 3;
      const int cd = (f & 7) ^ (r & 7);
      gload_lds16(Bt + (long)(col0 + r) * K + kt + cd * 8, lB + f * 16);
    }
    // A: reg-stage f32 -> bf16 -> LDS (same swizzled image as B's layout)
#pragma unroll
    for (int i = 0; i < 4; ++i) {
      const int f = i * 256 + tid;
      const int r = f >> 3;
      const int cs = (f & 7) ^ (r & 7);
      const float* src = A + (row0 + r) * (long)K + kt + cs * 8;
      const float4 a0 = *(const float4*)src;
      const float4 a1 = *(const float4*)(src + 4);
      u32x4 o;
      o[0] = f2bf(a0.x) | (f2bf(a0.y) << 16);
      o[1] = f2bf(a0.z) | (f2bf(a0.w) << 16);
      o[2] = f2bf(a1.x) | (f2bf(a1.y) << 16);
      o[3] = f2bf(a1.z) | (f2bf(a1.w) << 16);
      *(u32x4*)(lA + f * 16) = o;
    }
    __syncthreads();
#pragma unroll
    for (int kk = 0; kk < 2; ++kk) {
      bf16x8 af[4], bfv[4];
#pragma unroll
      for (int fm = 0; fm < 4; ++fm) {
        const int row = wr + fm * 16 + (lane & 15);
        const int ch = (kk * 4 + (lane >> 4)) ^ (row & 7);
        af[fm] = __builtin_bit_cast(bf16x8, *(const u32x4*)(lA + row * 128 + ch * 16));
      }
#pragma unroll
      for (int fn = 0; fn < 4; ++fn) {
        const int row = wc + fn * 16 + (lane & 15);
        const int ch = (kk * 4 + (lane >> 4)) ^ (row & 7);
        bfv[fn] = __builtin_bit_cast(bf16x8, *(const u32x4*)(lB + row * 128 + ch * 16));
      }
#pragma unroll
      for (int fm = 0; fm < 4; ++fm)
#pragma unroll
        for (int fn = 0; fn < 4; ++fn)
          acc[fm][fn] = __builtin_amdgcn_mfma_f32_16x16x32_bf16(af[fm], bfv[fn], acc[fm][fn], 0, 0, 0);
    }
    __syncthreads();
  }

#pragma unroll
  for (int fn = 0; fn < 4; ++fn) {
    const int n = col0 + wc + fn * 16 + (lane & 15);
    const float bn = bias[n];
#pragma unroll
    for (int fm = 0; fm < 4; ++fm) {
      const long mbase = row0 + wr + fm * 16 + ((lane >> 4) << 2);
#pragma unroll
      for (int j = 0; j < 4; ++j) {
        const float v = acc[fm][fn][j] + bn;
        Cout[(mbase + j) * (long)Ncols + n] = (unsigned short)f2bf(v);
      }
    }
  }
}

// ---------------- g2: proven R4 bf16 GEMM (A bf16, f32 out) ----------------
template<bool OUT_BF16>
__global__ __launch_bounds__(256, 4)
void gemm_bt(const unsigned short* __restrict__ A,
             const unsigned short* __restrict__ Bt,
             const float* __restrict__ bias,
             void* __restrict__ Cout,
             int Ncols, int K)
{
  __shared__ __align__(16) unsigned char lA[128 * 64 * 2];
  __shared__ __align__(16) unsigned char lB[128 * 64 * 2];
  const int tid = threadIdx.x;
  const int lane = tid & 63;
  const int wid = tid >> 6;
  const int wr = (wid >> 1) * 64;
  const int wc = (wid & 1) * 64;
  const int nbx = Ncols >> 7;
  const int bid = (int)blockIdx.x;
  const int cpx = (int)gridDim.x >> 3;
  const int swz = (bid & 7) * cpx + (bid >> 3);
  const int bx = swz % nbx;
  const int by = swz / nbx;
  const long row0 = (long)by << 7;
  const int col0 = bx << 7;

  f32x4 acc[4][4];
#pragma unroll
  for (int i = 0; i < 4; ++i)
#pragma unroll
    for (int j = 0; j < 4; ++j) acc[i][j] = (f32x4)0.0f;

  for (int kt = 0; kt < K; kt += 64) {
#pragma unroll
    for (int i = 0; i < 4; ++i) {
      const int f = i * 256 + tid;
      const int r = f >> 3;
      const int cd = (f & 7) ^ (r & 7);
      gload_lds16(A + (row0 + r) * (long)K + kt + cd * 8, lA + f * 16);
      gload_lds16(Bt + (long)(col0 + r) * K + kt + cd * 8, lB + f * 16);
    }
    __syncthreads();
#pragma unroll
    for (int kk = 0; kk < 2; ++kk) {
      bf16x8 af[4], bfv[4];
#pragma unroll
      for (int fm = 0; fm < 4; ++fm) {
        const int row = wr + fm * 16 + (lane & 15);
        const int ch = (kk * 4 + (lane >> 4)) ^ (row & 7);
        af[fm] = __builtin_bit_cast(bf16x8, *(const u32x4*)(lA + row * 128 + ch * 16));
      }
#pragma unroll
      for (int fn = 0; fn < 4; ++fn) {
        const int row = wc + fn * 16 + (lane & 15);
        const int ch = (kk * 4 + (lane >> 4)) ^ (row & 7);
        bfv[fn] = __builtin_bit_cast(bf16x8, *(const u32x4*)(lB + row * 128 + ch * 16));
      }
#pragma unroll
      for (int fm = 0; fm < 4; ++fm)
#pragma unroll
        for (int fn = 0; fn < 4; ++fn)
          acc[fm][fn] = __builtin_amdgcn_mfma_f32_16x16x32_bf16(af[fm], bfv[fn], acc[fm][fn], 0, 0, 0);
    }
    __syncthreads();
  }

#pragma unroll
  for (int fn = 0; fn < 4; ++fn) {
    const int n = col0 + wc + fn * 16 + (lane & 15);
    const float bn = bias[n];
#pragma unroll
    for (int fm = 0; fm < 4; ++fm) {
      const long mbase = row0 + wr + fm * 16 + ((lane >> 4) << 2);
#pragma unroll
      for (int j = 0; j < 4; ++j) {
        const float v = acc[fm][fn][j] + bn;
        if constexpr (OUT_BF16)
          ((unsigned short*)Cout)[(mbase + j) * (long)Ncols + n] = (unsigned short)f2bf(v);
        else
          ((float*)Cout)[(mbase + j) * (long)Ncols + n] = v;
      }
    }
  }
}

// One wave per (b,n) row. qkv row layout: [q(512) | k(512) | v(512)] bf16.
// All 6 gather loads issued before the reduce chains.
__global__ __launch_bounds__(256)
void nbr_attn(const unsigned short* __restrict__ qkv,
              const int* __restrict__ nbr,
              unsigned short* __restrict__ aout)
{
  const int wid = (int)((blockIdx.x * 256 + threadIdx.x) >> 6);
  const int lane = threadIdx.x & 63;
  const int n = wid & (SEQN - 1);
  const int b = wid >> 14;

  const unsigned short* qrow = qkv + (size_t)wid * 1536;
  const u32x4 qraw = *(const u32x4*)(qrow + lane * 8);

  int t0 = nbr[n];
  int t1 = nbr[SEQN + n];
  int t2 = nbr[2 * SEQN + n];
  bool val[3] = {t0 != -1, t1 != -1, t2 != -1};
  const unsigned short* base = qkv + (size_t)b * SEQN * 1536 + 512 + lane * 8;
  const unsigned short* k0 = base + (size_t)(t0 > 0 ? t0 : 0) * 1536;
  const unsigned short* k1 = base + (size_t)(t1 > 0 ? t1 : 0) * 1536;
  const unsigned short* k2 = base + (size_t)(t2 > 0 ? t2 : 0) * 1536;
  u32x4 kraw[3], vraw[3];
  kraw[0] = *(const u32x4*)k0;
  vraw[0] = *(const u32x4*)(k0 + 512);
  kraw[1] = *(const u32x4*)k1;
  vraw[1] = *(const u32x4*)(k1 + 512);
  kraw[2] = *(const u32x4*)k2;
  vraw[2] = *(const u32x4*)(k2 + 512);

  float qv[8];
#pragma unroll
  for (int i = 0; i < 4; ++i) {
    qv[2 * i] = bf2f(qraw[i] & 0xffffu);
    qv[2 * i + 1] = bf2f(qraw[i] >> 16);
  }
  float s[3];
#pragma unroll
  for (int k = 0; k < 3; ++k) {
    float d = 0.f;
#pragma unroll
    for (int i = 0; i < 4; ++i)
      d += qv[2 * i] * bf2f(kraw[k][i] & 0xffffu) + qv[2 * i + 1] * bf2f(kraw[k][i] >> 16);
    d += __shfl_xor(d, 1);
    d += __shfl_xor(d, 2);
    d += __shfl_xor(d, 4);
    s[k] = d * 0.125f;
  }
  float m = -3.0e38f;
#pragma unroll
  for (int k = 0; k < 3; ++k)
    if (val[k]) m = fmaxf(m, s[k]);
  float e[3], sum = 0.f;
#pragma unroll
  for (int k = 0; k < 3; ++k) {
    e[k] = val[k] ? __expf(s[k] - m) : 0.f;
    sum += e[k];
  }
  const float inv = sum > 0.f ? 1.f / sum : 0.f;
  float acc[8] = {0.f, 0.f, 0.f, 0.f, 0.f, 0.f, 0.f, 0.f};
#pragma unroll
  for (int k = 0; k < 3; ++k) {
    const float w = e[k] * inv;
#pragma unroll
    for (int i = 0; i < 4; ++i) {
      acc[2 * i] += w * bf2f(vraw[k][i] & 0xffffu);
      acc[2 * i + 1] += w * bf2f(vraw[k][i] >> 16);
    }
  }
  u32x4 o;
#pragma unroll
  for (int i = 0; i < 4; ++i)
    o[i] = f2bf(acc[2 * i]) | (f2bf(acc[2 * i + 1]) << 16);
  *(u32x4*)(aout + (size_t)wid * 512 + lane * 8) = o;
}

__global__ __launch_bounds__(256)
void prep_w(const float* __restrict__ Wq, const float* __restrict__ Wk,
            const float* __restrict__ Wv, const float* __restrict__ Wo,
            const float* __restrict__ bq, const float* __restrict__ bk,
            const float* __restrict__ bv,
            unsigned short* __restrict__ wf, unsigned short* __restrict__ wo,
            float* __restrict__ biasf)
{
  const int i = blockIdx.x * 256 + threadIdx.x;
  const int stride = gridDim.x * 256;
  for (int t = i; t < 262144; t += stride) {
    wf[t] = (unsigned short)f2bf(Wq[t]);
    wf[262144 + t] = (unsigned short)f2bf(Wk[t]);
    wf[524288 + t] = (unsigned short)f2bf(Wv[t]);
    wo[t] = (unsigned short)f2bf(Wo[t]);
  }
  if (i < 512) {
    biasf[i] = bq[i];
    biasf[512 + i] = bk[i];
    biasf[1024 + i] = bv[i];
  }
}

extern "C" void kernel_launch(void* const* d_in, const int* in_sizes, int n_in,
                              void* d_out, int out_size, void* d_ws, size_t ws_size,
                              hipStream_t stream) {
  const float* x  = (const float*)d_in[0];
  const int* nbr  = (const int*)d_in[1];
  const float* Wq = (const float*)d_in[2];
  const float* bq = (const float*)d_in[3];
  const float* Wk = (const float*)d_in[4];
  const float* bk = (const float*)d_in[5];
  const float* Wv = (const float*)d_in[6];
  const float* bv = (const float*)d_in[7];
  const float* Wo = (const float*)d_in[8];
  const float* bo = (const float*)d_in[9];
  float* out = (float*)d_out;
  unsigned char* ws = (unsigned char*)d_ws;

  // ws layout (bytes):
  //   [0, 64Mi)            attn_out bf16 (65536*512*2)
  //   [64Mi, 256Mi)        qkv bf16 (65536*1536*2 = 192Mi)
  //   [256Mi, +1.5Mi)      fused W (Wq;Wk;Wv) bf16 [1536][512]
  //   [..., +0.5Mi)        Wo bf16 [512][512]
  //   [..., +6Ki)          fused bias f32 [1536]
  unsigned short* ao  = (unsigned short*)(ws);
  unsigned short* qkv = (unsigned short*)(ws + 67108864UL);
  unsigned short* wf  = (unsigned short*)(ws + 268435456UL);
  unsigned short* wo  = (unsigned short*)(ws + 270008320UL);
  float* biasf        = (float*)(ws + 270532608UL);

  prep_w<<<1024, 256, 0, stream>>>(Wq, Wk, Wv, Wo, bq, bk, bv, wf, wo, biasf);
  // QKV projection with fused f32->bf16: M=65536, N=1536, K=512
  gemm_a32<<<dim3(512 * 12), 256, 0, stream>>>(x, wf, biasf, qkv, 1536, 512);
  // neighbor attention
  nbr_attn<<<16384, 256, 0, stream>>>(qkv, nbr, ao);
  // output projection: M=65536, N=512, K=512, f32 out
  gemm_bt<false><<<dim3(512 * 4), 256, 0, stream>>>(ao, wo, bo, out, 512, 512);
}

// Round 7
// 300.723 us; speedup vs baseline: 1.2103x; 1.2103x over previous
//
#include <hip/hip_runtime.h>
#include <stdint.h>

#define SEQN 16384
#define NBATCH 4

typedef __attribute__((ext_vector_type(8))) __bf16 bf16x8;
typedef __attribute__((ext_vector_type(4))) float f32x4;
typedef __attribute__((ext_vector_type(4))) unsigned int u32x4;

__device__ __forceinline__ unsigned int f2bf(float f) {
  unsigned int x = __builtin_bit_cast(unsigned int, f);
  x = x + 0x7fffu + ((x >> 16) & 1u);
  return x >> 16;
}
__device__ __forceinline__ float bf2f(unsigned int lo) {
  return __builtin_bit_cast(float, lo << 16);
}

__device__ __forceinline__ void gload_lds16(const unsigned short* g, unsigned char* l) {
  __builtin_amdgcn_global_load_lds(
      (const __attribute__((address_space(1))) unsigned int*)g,
      (__attribute__((address_space(3))) unsigned int*)l, 16, 0, 0);
}

// Raw workgroup barrier WITHOUT the vmcnt(0)/lgkmcnt(0) drain of __syncthreads.
__device__ __forceinline__ void barrier_raw() {
  asm volatile("" ::: "memory");
  __builtin_amdgcn_s_barrier();
  asm volatile("" ::: "memory");
}

// ---------------- g1: counted-vmcnt ring GEMM, 128x128, BK=32 --------------
// C = A @ Bt^T + bias. A:[M][512] bf16, Bt:[Ncols][512] bf16 (both row-major).
// 4 waves (2x2), ring of 4 x 16KiB buffers (64 KiB LDS -> 2 blocks/CU so
// cross-block overlap covers barrier stalls). Per tile t (one phase):
//   WAITVM(4): outstanding {t+1,t+2}=8 -> retires tile t+1 under ANY
//     scheduler placement (sink past <=4 STAGE loads -> <=12 outstanding,
//     vmcnt(4) retires >=8 >= tile t+1). Tile-t landing for ALL waves was
//     established at iter t-1 (its wait retired t, its barriers synced), so
//     this phase's ds_reads may legally precede the barrier (latency overlap).
//   STAGE(t+3): 4 gload_lds into buf (t+3)&3; that buffer's last readers
//     (iter t-1) all retired reads before iter t-1's closing barrier.
//   ds_read 8x b128 -> barrier -> lgkmcnt(0)+sched_barrier (rule 18) ->
//   setprio(1) 16 MFMA setprio(0) -> closing barrier (protects buf t&3 from
//   iter t+1's STAGE).
// LDS granule layout (16B granules, 4/row): g = r*4 + (c ^ ((r>>1)&3)),
// applied via pre-permuted global source + permuted ds_read (rule #21);
// measured 0 bank conflicts (R5). XCD-chunked block swizzle (T1).
template<bool OUT_BF16>
__global__ __launch_bounds__(256, 2)
void gemm_ring(const unsigned short* __restrict__ A,
               const unsigned short* __restrict__ Bt,
               const float* __restrict__ bias,
               void* __restrict__ Cout,
               int Ncols)
{
  __shared__ __align__(16) unsigned char smem[65536];  // 4 bufs x (8K A + 8K B)
  const int K = 512;
  const int tid = threadIdx.x;
  const int lane = tid & 63;
  const int wid = tid >> 6;
  const int wr = (wid >> 1) * 64;
  const int wc = (wid & 1) * 64;
  const int nbx = Ncols >> 7;
  const int bid = (int)blockIdx.x;
  const int cpx = (int)gridDim.x >> 3;
  const int swz = (bid & 7) * cpx + (bid >> 3);   // XCD swizzle (grid%8==0)
  const int bx = swz % nbx;
  const int by = swz / nbx;
  const long row0 = (long)by << 7;
  const int col0 = bx << 7;

  // stage sources: granule g (A: g=tid -> rows 0..63; g=256+tid -> rows 64..127)
  // holds source chunk c = (g&3) ^ ((r>>1)&3), r = g>>2.
  int srcA0, srcA1, srcB0, srcB1;
  {
    const int r0 = tid >> 2, c0 = (tid & 3) ^ ((r0 >> 1) & 3);
    const int r1 = 64 + (tid >> 2), c1 = (tid & 3) ^ ((r1 >> 1) & 3);
    srcA0 = (int)(row0 + r0) * K + c0 * 8;
    srcA1 = (int)(row0 + r1) * K + c1 * 8;
    srcB0 = (col0 + r0) * K + c0 * 8;
    srcB1 = (col0 + r1) * K + c1 * 8;
  }

  // frag ds_read byte offsets within a matrix region (row stride 64 B)
  int aoff[4], boff[4];
#pragma unroll
  for (int fm = 0; fm < 4; ++fm) {
    const int r = wr + fm * 16 + (lane & 15);
    aoff[fm] = r * 64 + ((((lane >> 4)) ^ ((r >> 1) & 3)) << 4);
  }
#pragma unroll
  for (int fn = 0; fn < 4; ++fn) {
    const int r = wc + fn * 16 + (lane & 15);
    boff[fn] = r * 64 + ((((lane >> 4)) ^ ((r >> 1) & 3)) << 4);
  }

  f32x4 acc[4][4];
#pragma unroll
  for (int i = 0; i < 4; ++i)
#pragma unroll
    for (int j = 0; j < 4; ++j) acc[i][j] = (f32x4)0.0f;

#define STAGE(t)                                                            \
  {                                                                         \
    unsigned char* buf_ = smem + ((t) & 3) * 16384;                         \
    const int kt_ = (t) * 32;                                               \
    gload_lds16(A + srcA0 + kt_, buf_ + tid * 16);                          \
    gload_lds16(A + srcA1 + kt_, buf_ + 4096 + tid * 16);                   \
    gload_lds16(Bt + srcB0 + kt_, buf_ + 8192 + tid * 16);                  \
    gload_lds16(Bt + srcB1 + kt_, buf_ + 12288 + tid * 16);                 \
  }

#define DSREAD(t)                                                           \
  const unsigned char* buf_ = smem + ((t) & 3) * 16384;                     \
  bf16x8 af[4], bfv[4];                                                     \
  _Pragma("unroll")                                                         \
  for (int fm = 0; fm < 4; ++fm)                                            \
    af[fm] = __builtin_bit_cast(bf16x8, *(const u32x4*)(buf_ + aoff[fm]));  \
  _Pragma("unroll")                                                         \
  for (int fn = 0; fn < 4; ++fn)                                            \
    bfv[fn] = __builtin_bit_cast(bf16x8,                                    \
                  *(const u32x4*)(buf_ + 8192 + boff[fn]));

#define MFMA16()                                                            \
  asm volatile("s_waitcnt lgkmcnt(0)" ::: "memory");                        \
  __builtin_amdgcn_sched_barrier(0);                                        \
  __builtin_amdgcn_s_setprio(1);                                            \
  _Pragma("unroll")                                                         \
  for (int fm = 0; fm < 4; ++fm)                                            \
    _Pragma("unroll")                                                       \
    for (int fn = 0; fn < 4; ++fn)                                          \
      acc[fm][fn] = __builtin_amdgcn_mfma_f32_16x16x32_bf16(                \
          af[fm], bfv[fn], acc[fm][fn], 0, 0, 0);                           \
  __builtin_amdgcn_s_setprio(0);                                            \
  __builtin_amdgcn_sched_barrier(0);

#define WAITVM(n)                                                           \
  __builtin_amdgcn_sched_barrier(0);                                        \
  asm volatile("s_waitcnt vmcnt(" #n ")" ::: "memory");                     \
  __builtin_amdgcn_sched_barrier(0);

  STAGE(0); STAGE(1); STAGE(2);
  WAITVM(8);            // retires tile 0
  barrier_raw();        // tile 0 landed for all waves
  for (int t = 0; t < 13; ++t) {
    WAITVM(4);          // retires tile t+1 (any placement)
    STAGE(t + 3);
    DSREAD(t);
    barrier_raw();
    MFMA16();
    barrier_raw();      // protects buf t&3 from iter t+1's STAGE
  }
  { WAITVM(4); DSREAD(13); barrier_raw(); MFMA16(); barrier_raw(); }
  { WAITVM(0); DSREAD(14); barrier_raw(); MFMA16(); barrier_raw(); }
  { DSREAD(15); MFMA16(); }
#undef STAGE
#undef DSREAD
#undef MFMA16
#undef WAITVM

#pragma unroll
  for (int fn = 0; fn < 4; ++fn) {
    const int n = col0 + wc + fn * 16 + (lane & 15);
    const float bn = bias[n];
#pragma unroll
    for (int fm = 0; fm < 4; ++fm) {
      const long mbase = row0 + wr + fm * 16 + ((lane >> 4) << 2);
#pragma unroll
      for (int j = 0; j < 4; ++j) {
        const float v = acc[fm][fn][j] + bn;
        if constexpr (OUT_BF16)
          ((unsigned short*)Cout)[(mbase + j) * (long)Ncols + n] = (unsigned short)f2bf(v);
        else
          ((float*)Cout)[(mbase + j) * (long)Ncols + n] = v;
      }
    }
  }
}

// ---------------- g2: proven R4 bf16 GEMM (2-barrier drain loop) -----------
template<bool OUT_BF16>
__global__ __launch_bounds__(256, 4)
void gemm_bt(const unsigned short* __restrict__ A,
             const unsigned short* __restrict__ Bt,
             const float* __restrict__ bias,
             void* __restrict__ Cout,
             int Ncols, int K)
{
  __shared__ __align__(16) unsigned char lA[128 * 64 * 2];
  __shared__ __align__(16) unsigned char lB[128 * 64 * 2];
  const int tid = threadIdx.x;
  const int lane = tid & 63;
  const int wid = tid >> 6;
  const int wr = (wid >> 1) * 64;
  const int wc = (wid & 1) * 64;
  const int nbx = Ncols >> 7;
  const int bid = (int)blockIdx.x;
  const int cpx = (int)gridDim.x >> 3;
  const int swz = (bid & 7) * cpx + (bid >> 3);
  const int bx = swz % nbx;
  const int by = swz / nbx;
  const long row0 = (long)by << 7;
  const int col0 = bx << 7;

  f32x4 acc[4][4];
#pragma unroll
  for (int i = 0; i < 4; ++i)
#pragma unroll
    for (int j = 0; j < 4; ++j) acc[i][j] = (f32x4)0.0f;

  for (int kt = 0; kt < K; kt += 64) {
#pragma unroll
    for (int i = 0; i < 4; ++i) {
      const int f = i * 256 + tid;
      const int r = f >> 3;
      const int cd = (f & 7) ^ (r & 7);
      gload_lds16(A + (row0 + r) * (long)K + kt + cd * 8, lA + f * 16);
      gload_lds16(Bt + (long)(col0 + r) * K + kt + cd * 8, lB + f * 16);
    }
    __syncthreads();
#pragma unroll
    for (int kk = 0; kk < 2; ++kk) {
      bf16x8 af[4], bfv[4];
#pragma unroll
      for (int fm = 0; fm < 4; ++fm) {
        const int row = wr + fm * 16 + (lane & 15);
        const int ch = (kk * 4 + (lane >> 4)) ^ (row & 7);
        af[fm] = __builtin_bit_cast(bf16x8, *(const u32x4*)(lA + row * 128 + ch * 16));
      }
#pragma unroll
      for (int fn = 0; fn < 4; ++fn) {
        const int row = wc + fn * 16 + (lane & 15);
        const int ch = (kk * 4 + (lane >> 4)) ^ (row & 7);
        bfv[fn] = __builtin_bit_cast(bf16x8, *(const u32x4*)(lB + row * 128 + ch * 16));
      }
#pragma unroll
      for (int fm = 0; fm < 4; ++fm)
#pragma unroll
        for (int fn = 0; fn < 4; ++fn)
          acc[fm][fn] = __builtin_amdgcn_mfma_f32_16x16x32_bf16(af[fm], bfv[fn], acc[fm][fn], 0, 0, 0);
    }
    __syncthreads();
  }

#pragma unroll
  for (int fn = 0; fn < 4; ++fn) {
    const int n = col0 + wc + fn * 16 + (lane & 15);
    const float bn = bias[n];
#pragma unroll
    for (int fm = 0; fm < 4; ++fm) {
      const long mbase = row0 + wr + fm * 16 + ((lane >> 4) << 2);
#pragma unroll
      for (int j = 0; j < 4; ++j) {
        const float v = acc[fm][fn][j] + bn;
        if constexpr (OUT_BF16)
          ((unsigned short*)Cout)[(mbase + j) * (long)Ncols + n] = (unsigned short)f2bf(v);
        else
          ((float*)Cout)[(mbase + j) * (long)Ncols + n] = v;
      }
    }
  }
}

// One wave per (b,n) row. qkv row layout: [q(512) | k(512) | v(512)] bf16.
__global__ __launch_bounds__(256)
void nbr_attn(const unsigned short* __restrict__ qkv,
              const int* __restrict__ nbr,
              unsigned short* __restrict__ aout)
{
  const int wid = (int)((blockIdx.x * 256 + threadIdx.x) >> 6);
  const int lane = threadIdx.x & 63;
  const int n = wid & (SEQN - 1);
  const int b = wid >> 14;

  const unsigned short* qrow = qkv + (size_t)wid * 1536;
  const u32x4 qraw = *(const u32x4*)(qrow + lane * 8);

  int t0 = nbr[n];
  int t1 = nbr[SEQN + n];
  int t2 = nbr[2 * SEQN + n];
  bool val[3] = {t0 != -1, t1 != -1, t2 != -1};
  const unsigned short* base = qkv + (size_t)b * SEQN * 1536 + 512 + lane * 8;
  const unsigned short* k0 = base + (size_t)(t0 > 0 ? t0 : 0) * 1536;
  const unsigned short* k1 = base + (size_t)(t1 > 0 ? t1 : 0) * 1536;
  const unsigned short* k2 = base + (size_t)(t2 > 0 ? t2 : 0) * 1536;
  u32x4 kraw[3], vraw[3];
  kraw[0] = *(const u32x4*)k0;
  vraw[0] = *(const u32x4*)(k0 + 512);
  kraw[1] = *(const u32x4*)k1;
  vraw[1] = *(const u32x4*)(k1 + 512);
  kraw[2] = *(const u32x4*)k2;
  vraw[2] = *(const u32x4*)(k2 + 512);

  float qv[8];
#pragma unroll
  for (int i = 0; i < 4; ++i) {
    qv[2 * i] = bf2f(qraw[i] & 0xffffu);
    qv[2 * i + 1] = bf2f(qraw[i] >> 16);
  }
  float s[3];
#pragma unroll
  for (int k = 0; k < 3; ++k) {
    float d = 0.f;
#pragma unroll
    for (int i = 0; i < 4; ++i)
      d += qv[2 * i] * bf2f(kraw[k][i] & 0xffffu) + qv[2 * i + 1] * bf2f(kraw[k][i] >> 16);
    d += __shfl_xor(d, 1);
    d += __shfl_xor(d, 2);
    d += __shfl_xor(d, 4);
    s[k] = d * 0.125f;
  }
  float m = -3.0e38f;
#pragma unroll
  for (int k = 0; k < 3; ++k)
    if (val[k]) m = fmaxf(m, s[k]);
  float e[3], sum = 0.f;
#pragma unroll
  for (int k = 0; k < 3; ++k) {
    e[k] = val[k] ? __expf(s[k] - m) : 0.f;
    sum += e[k];
  }
  const float inv = sum > 0.f ? 1.f / sum : 0.f;
  float acc[8] = {0.f, 0.f, 0.f, 0.f, 0.f, 0.f, 0.f, 0.f};
#pragma unroll
  for (int k = 0; k < 3; ++k) {
    const float w = e[k] * inv;
#pragma unroll
    for (int i = 0; i < 4; ++i) {
      acc[2 * i] += w * bf2f(vraw[k][i] & 0xffffu);
      acc[2 * i + 1] += w * bf2f(vraw[k][i] >> 16);
    }
  }
  u32x4 o;
#pragma unroll
  for (int i = 0; i < 4; ++i)
    o[i] = f2bf(acc[2 * i]) | (f2bf(acc[2 * i + 1]) << 16);
  *(u32x4*)(aout + (size_t)wid * 512 + lane * 8) = o;
}

__global__ __launch_bounds__(256)
void cvt_f32_bf16(const float* __restrict__ in, unsigned short* __restrict__ out, int n8) {
  int i = blockIdx.x * 256 + threadIdx.x;
  const int stride = gridDim.x * 256;
  for (; i < n8; i += stride) {
    const float4* p = (const float4*)(in + (size_t)i * 8);
    const float4 a = p[0], c = p[1];
    u32x4 o;
    o[0] = f2bf(a.x) | (f2bf(a.y) << 16);
    o[1] = f2bf(a.z) | (f2bf(a.w) << 16);
    o[2] = f2bf(c.x) | (f2bf(c.y) << 16);
    o[3] = f2bf(c.z) | (f2bf(c.w) << 16);
    *(u32x4*)(out + (size_t)i * 8) = o;
  }
}

__global__ __launch_bounds__(256)
void prep_w(const float* __restrict__ Wq, const float* __restrict__ Wk,
            const float* __restrict__ Wv, const float* __restrict__ Wo,
            const float* __restrict__ bq, const float* __restrict__ bk,
            const float* __restrict__ bv,
            unsigned short* __restrict__ wf, unsigned short* __restrict__ wo,
            float* __restrict__ biasf)
{
  const int i = blockIdx.x * 256 + threadIdx.x;
  const int stride = gridDim.x * 256;
  for (int t = i; t < 262144; t += stride) {
    wf[t] = (unsigned short)f2bf(Wq[t]);
    wf[262144 + t] = (unsigned short)f2bf(Wk[t]);
    wf[524288 + t] = (unsigned short)f2bf(Wv[t]);
    wo[t] = (unsigned short)f2bf(Wo[t]);
  }
  if (i < 512) {
    biasf[i] = bq[i];
    biasf[512 + i] = bk[i];
    biasf[1024 + i] = bv[i];
  }
}

extern "C" void kernel_launch(void* const* d_in, const int* in_sizes, int n_in,
                              void* d_out, int out_size, void* d_ws, size_t ws_size,
                              hipStream_t stream) {
  const float* x  = (const float*)d_in[0];
  const int* nbr  = (const int*)d_in[1];
  const float* Wq = (const float*)d_in[2];
  const float* bq = (const float*)d_in[3];
  const float* Wk = (const float*)d_in[4];
  const float* bk = (const float*)d_in[5];
  const float* Wv = (const float*)d_in[6];
  const float* bv = (const float*)d_in[7];
  const float* Wo = (const float*)d_in[8];
  const float* bo = (const float*)d_in[9];
  float* out = (float*)d_out;
  unsigned char* ws = (unsigned char*)d_ws;

  // ws layout (bytes):
  //   [0, 64Mi)            x_bf16, later reused as attn_out_bf16
  //   [64Mi, 256Mi)        qkv bf16 (65536*1536*2 = 192Mi)
  //   [256Mi, +1.5Mi)      fused W (Wq;Wk;Wv) bf16 [1536][512]
  //   [..., +0.5Mi)        Wo bf16 [512][512]
  //   [..., +6Ki)          fused bias f32 [1536]
  unsigned short* xb  = (unsigned short*)(ws);
  unsigned short* qkv = (unsigned short*)(ws + 67108864UL);
  unsigned short* wf  = (unsigned short*)(ws + 268435456UL);
  unsigned short* wo  = (unsigned short*)(ws + 270008320UL);
  float* biasf        = (float*)(ws + 270532608UL);

  cvt_f32_bf16<<<4096, 256, 0, stream>>>(x, xb, 33554432 / 8);
  prep_w<<<1024, 256, 0, stream>>>(Wq, Wk, Wv, Wo, bq, bk, bv, wf, wo, biasf);
  // QKV projection: M=65536, N=1536 -> grid 512*12 = 6144 (%8==0)
  gemm_ring<true><<<dim3(512 * 12), 256, 0, stream>>>(xb, wf, biasf, qkv, 1536);
  // neighbor attention (reuses xb region for output; x_bf16 is dead)
  nbr_attn<<<16384, 256, 0, stream>>>(qkv, nbr, xb);
  // output projection: M=65536, N=512, K=512, f32 out (proven kernel)
  gemm_bt<false><<<dim3(512 * 4), 256, 0, stream>>>(xb, wo, bo, out, 512, 512);
}

// Round 8
// 283.186 us; speedup vs baseline: 1.2852x; 1.0619x over previous
//
#include <hip/hip_runtime.h>
#include <stdint.h>

#define SEQN 16384
#define NBATCH 4

typedef __attribute__((ext_vector_type(8))) __bf16 bf16x8;
typedef __attribute__((ext_vector_type(4))) float f32x4;
typedef __attribute__((ext_vector_type(4))) unsigned int u32x4;

__device__ __forceinline__ unsigned int f2bf(float f) {
  unsigned int x = __builtin_bit_cast(unsigned int, f);
  x = x + 0x7fffu + ((x >> 16) & 1u);
  return x >> 16;
}
__device__ __forceinline__ float bf2f(unsigned int lo) {
  return __builtin_bit_cast(float, lo << 16);
}

__device__ __forceinline__ void gload_lds16(const unsigned short* g, unsigned char* l) {
  __builtin_amdgcn_global_load_lds(
      (const __attribute__((address_space(1))) unsigned int*)g,
      (__attribute__((address_space(3))) unsigned int*)l, 16, 0, 0);
}

// C = A @ Bt^T + bias.  A: [M][K] bf16 row-major, Bt: [Ncols][K] bf16 row-major.
// Proven m97-style 128x128 tile, BK=64, 4 waves (2x2), 2-barrier loop
// (__syncthreads drain semantics — stable across graph replays).
// LDS XOR-swizzle via pre-swizzled global source (rule #21), 0 bank conflicts.
// XCD-chunked block swizzle (T1, gridDim%8==0 -> bijective).
template<bool OUT_BF16>
__global__ __launch_bounds__(256, 4)
void gemm_bt(const unsigned short* __restrict__ A,
             const unsigned short* __restrict__ Bt,
             const float* __restrict__ bias,
             void* __restrict__ Cout,
             int Ncols, int K)
{
  __shared__ __align__(16) unsigned char lA[128 * 64 * 2];
  __shared__ __align__(16) unsigned char lB[128 * 64 * 2];
  const int tid = threadIdx.x;
  const int lane = tid & 63;
  const int wid = tid >> 6;
  const int wr = (wid >> 1) * 64;   // wave row offset in tile
  const int wc = (wid & 1) * 64;    // wave col offset in tile
  const int nbx = Ncols >> 7;
  const int bid = (int)blockIdx.x;
  const int cpx = (int)gridDim.x >> 3;
  const int swz = (bid & 7) * cpx + (bid >> 3);
  const int bx = swz % nbx;
  const int by = swz / nbx;
  const long row0 = (long)by << 7;
  const int col0 = bx << 7;

  f32x4 acc[4][4];
#pragma unroll
  for (int i = 0; i < 4; ++i)
#pragma unroll
    for (int j = 0; j < 4; ++j) acc[i][j] = (f32x4)0.0f;

  for (int kt = 0; kt < K; kt += 64) {
#pragma unroll
    for (int i = 0; i < 4; ++i) {
      const int f = i * 256 + tid;          // 16B chunk index 0..1023
      const int r = f >> 3;                 // tile row 0..127
      const int cd = (f & 7) ^ (r & 7);     // inverse-swizzled source chunk
      gload_lds16(A + (row0 + r) * (long)K + kt + cd * 8, lA + f * 16);
      gload_lds16(Bt + (long)(col0 + r) * K + kt + cd * 8, lB + f * 16);
    }
    __syncthreads();
#pragma unroll
    for (int kk = 0; kk < 2; ++kk) {
      bf16x8 af[4], bfv[4];
#pragma unroll
      for (int fm = 0; fm < 4; ++fm) {
        const int row = wr + fm * 16 + (lane & 15);
        const int ch = (kk * 4 + (lane >> 4)) ^ (row & 7);
        af[fm] = __builtin_bit_cast(bf16x8, *(const u32x4*)(lA + row * 128 + ch * 16));
      }
#pragma unroll
      for (int fn = 0; fn < 4; ++fn) {
        const int row = wc + fn * 16 + (lane & 15);
        const int ch = (kk * 4 + (lane >> 4)) ^ (row & 7);
        bfv[fn] = __builtin_bit_cast(bf16x8, *(const u32x4*)(lB + row * 128 + ch * 16));
      }
#pragma unroll
      for (int fm = 0; fm < 4; ++fm)
#pragma unroll
        for (int fn = 0; fn < 4; ++fn)
          acc[fm][fn] = __builtin_amdgcn_mfma_f32_16x16x32_bf16(af[fm], bfv[fn], acc[fm][fn], 0, 0, 0);
    }
    __syncthreads();
  }

#pragma unroll
  for (int fn = 0; fn < 4; ++fn) {
    const int n = col0 + wc + fn * 16 + (lane & 15);
    const float bn = bias[n];
#pragma unroll
    for (int fm = 0; fm < 4; ++fm) {
      const long mbase = row0 + wr + fm * 16 + ((lane >> 4) << 2);
#pragma unroll
      for (int j = 0; j < 4; ++j) {
        const float v = acc[fm][fn][j] + bn;
        if constexpr (OUT_BF16)
          ((unsigned short*)Cout)[(mbase + j) * (long)Ncols + n] = (unsigned short)f2bf(v);
        else
          ((float*)Cout)[(mbase + j) * (long)Ncols + n] = v;
      }
    }
  }
}

// One wave per (b,n) row. qkv row layout: [q(512) | k(512) | v(512)] bf16.
// lane l covers dims [l*8, l*8+8) == head h=l>>3, d-segment (l&7)*8.
// All 6 gather loads (3x K-row, 3x V-row) issued before the reduce chains.
__global__ __launch_bounds__(256)
void nbr_attn(const unsigned short* __restrict__ qkv,
              const int* __restrict__ nbr,
              unsigned short* __restrict__ aout)
{
  const int wid = (int)((blockIdx.x * 256 + threadIdx.x) >> 6);
  const int lane = threadIdx.x & 63;
  const int n = wid & (SEQN - 1);
  const int b = wid >> 14;

  const unsigned short* qrow = qkv + (size_t)wid * 1536;
  const u32x4 qraw = *(const u32x4*)(qrow + lane * 8);

  int t0 = nbr[n];
  int t1 = nbr[SEQN + n];
  int t2 = nbr[2 * SEQN + n];
  bool val[3] = {t0 != -1, t1 != -1, t2 != -1};
  const unsigned short* base = qkv + (size_t)b * SEQN * 1536 + 512 + lane * 8;
  const unsigned short* k0 = base + (size_t)(t0 > 0 ? t0 : 0) * 1536;
  const unsigned short* k1 = base + (size_t)(t1 > 0 ? t1 : 0) * 1536;
  const unsigned short* k2 = base + (size_t)(t2 > 0 ? t2 : 0) * 1536;
  u32x4 kraw[3], vraw[3];
  kraw[0] = *(const u32x4*)k0;
  vraw[0] = *(const u32x4*)(k0 + 512);
  kraw[1] = *(const u32x4*)k1;
  vraw[1] = *(const u32x4*)(k1 + 512);
  kraw[2] = *(const u32x4*)k2;
  vraw[2] = *(const u32x4*)(k2 + 512);

  float qv[8];
#pragma unroll
  for (int i = 0; i < 4; ++i) {
    qv[2 * i] = bf2f(qraw[i] & 0xffffu);
    qv[2 * i + 1] = bf2f(qraw[i] >> 16);
  }
  float s[3];
#pragma unroll
  for (int k = 0; k < 3; ++k) {
    float d = 0.f;
#pragma unroll
    for (int i = 0; i < 4; ++i)
      d += qv[2 * i] * bf2f(kraw[k][i] & 0xffffu) + qv[2 * i + 1] * bf2f(kraw[k][i] >> 16);
    d += __shfl_xor(d, 1);
    d += __shfl_xor(d, 2);
    d += __shfl_xor(d, 4);
    s[k] = d * 0.125f;
  }
  float m = -3.0e38f;
#pragma unroll
  for (int k = 0; k < 3; ++k)
    if (val[k]) m = fmaxf(m, s[k]);
  float e[3], sum = 0.f;
#pragma unroll
  for (int k = 0; k < 3; ++k) {
    e[k] = val[k] ? __expf(s[k] - m) : 0.f;
    sum += e[k];
  }
  const float inv = sum > 0.f ? 1.f / sum : 0.f;
  float acc[8] = {0.f, 0.f, 0.f, 0.f, 0.f, 0.f, 0.f, 0.f};
#pragma unroll
  for (int k = 0; k < 3; ++k) {
    const float w = e[k] * inv;
#pragma unroll
    for (int i = 0; i < 4; ++i) {
      acc[2 * i] += w * bf2f(vraw[k][i] & 0xffffu);
      acc[2 * i + 1] += w * bf2f(vraw[k][i] >> 16);
    }
  }
  u32x4 o;
#pragma unroll
  for (int i = 0; i < 4; ++i)
    o[i] = f2bf(acc[2 * i]) | (f2bf(acc[2 * i + 1]) << 16);
  *(u32x4*)(aout + (size_t)wid * 512 + lane * 8) = o;
}

// Fused x f32->bf16 conversion + weight/bias prep (one dispatch).
// grid 4096*256 = 1048576 threads; x has 4194304 float8-groups (4 iters/thread);
// weights 262144 elems handled by the first 262144 threads.
__global__ __launch_bounds__(256)
void cvt_prep(const float* __restrict__ x, unsigned short* __restrict__ xb,
              const float* __restrict__ Wq, const float* __restrict__ Wk,
              const float* __restrict__ Wv, const float* __restrict__ Wo,
              const float* __restrict__ bq, const float* __restrict__ bk,
              const float* __restrict__ bv,
              unsigned short* __restrict__ wf, unsigned short* __restrict__ wo,
              float* __restrict__ biasf)
{
  const int i = blockIdx.x * 256 + threadIdx.x;
  if (i < 262144) {
    wf[i] = (unsigned short)f2bf(Wq[i]);
    wf[262144 + i] = (unsigned short)f2bf(Wk[i]);
    wf[524288 + i] = (unsigned short)f2bf(Wv[i]);
    wo[i] = (unsigned short)f2bf(Wo[i]);
  }
  if (i < 512) {
    biasf[i] = bq[i];
    biasf[512 + i] = bk[i];
    biasf[1024 + i] = bv[i];
  }
#pragma unroll
  for (int t = i; t < 4194304; t += 1048576) {
    const float4* p = (const float4*)(x + (size_t)t * 8);
    const float4 a = p[0], c = p[1];
    u32x4 o;
    o[0] = f2bf(a.x) | (f2bf(a.y) << 16);
    o[1] = f2bf(a.z) | (f2bf(a.w) << 16);
    o[2] = f2bf(c.x) | (f2bf(c.y) << 16);
    o[3] = f2bf(c.z) | (f2bf(c.w) << 16);
    *(u32x4*)(xb + (size_t)t * 8) = o;
  }
}

extern "C" void kernel_launch(void* const* d_in, const int* in_sizes, int n_in,
                              void* d_out, int out_size, void* d_ws, size_t ws_size,
                              hipStream_t stream) {
  const float* x  = (const float*)d_in[0];
  const int* nbr  = (const int*)d_in[1];
  const float* Wq = (const float*)d_in[2];
  const float* bq = (const float*)d_in[3];
  const float* Wk = (const float*)d_in[4];
  const float* bk = (const float*)d_in[5];
  const float* Wv = (const float*)d_in[6];
  const float* bv = (const float*)d_in[7];
  const float* Wo = (const float*)d_in[8];
  const float* bo = (const float*)d_in[9];
  float* out = (float*)d_out;
  unsigned char* ws = (unsigned char*)d_ws;

  // ws layout (bytes):
  //   [0, 64Mi)            x_bf16, later reused as attn_out_bf16 (65536*512*2)
  //   [64Mi, 256Mi)        qkv bf16 (65536*1536*2 = 192Mi)
  //   [256Mi, +1.5Mi)      fused W (Wq;Wk;Wv) bf16 [1536][512]
  //   [..., +0.5Mi)        Wo bf16 [512][512]
  //   [..., +6Ki)          fused bias f32 [1536]
  unsigned short* xb  = (unsigned short*)(ws);
  unsigned short* qkv = (unsigned short*)(ws + 67108864UL);
  unsigned short* wf  = (unsigned short*)(ws + 268435456UL);
  unsigned short* wo  = (unsigned short*)(ws + 270008320UL);
  float* biasf        = (float*)(ws + 270532608UL);

  cvt_prep<<<4096, 256, 0, stream>>>(x, xb, Wq, Wk, Wv, Wo, bq, bk, bv, wf, wo, biasf);
  // QKV projection: M=65536, N=1536, K=512
  gemm_bt<true><<<dim3(512 * 12), 256, 0, stream>>>(xb, wf, biasf, qkv, 1536, 512);
  // neighbor attention (reuses xb region for output; x_bf16 is dead)
  nbr_attn<<<16384, 256, 0, stream>>>(qkv, nbr, xb);
  // output projection: M=65536, N=512, K=512, f32 out
  gemm_bt<false><<<dim3(512 * 4), 256, 0, stream>>>(xb, wo, bo, out, 512, 512);
}

// Round 9
// 282.005 us; speedup vs baseline: 1.2906x; 1.0042x over previous
//
#include <hip/hip_runtime.h>
#include <stdint.h>

#define SEQN 16384
#define NBATCH 4

typedef __attribute__((ext_vector_type(8))) __bf16 bf16x8;
typedef __attribute__((ext_vector_type(4))) float f32x4;
typedef __attribute__((ext_vector_type(4))) unsigned int u32x4;

__device__ __forceinline__ unsigned int f2bf(float f) {
  unsigned int x = __builtin_bit_cast(unsigned int, f);
  x = x + 0x7fffu + ((x >> 16) & 1u);
  return x >> 16;
}
__device__ __forceinline__ float bf2f(unsigned int lo) {
  return __builtin_bit_cast(float, lo << 16);
}

__device__ __forceinline__ void gload_lds16(const unsigned short* g, unsigned char* l) {
  __builtin_amdgcn_global_load_lds(
      (const __attribute__((address_space(1))) unsigned int*)g,
      (__attribute__((address_space(3))) unsigned int*)l, 16, 0, 0);
}

// C = A @ Bt^T + bias.  A: [M][K] bf16 row-major, Bt: [Ncols][K] bf16 row-major.
// Proven m97-style 128x128 tile, BK=64, 4 waves (2x2), 2-barrier loop
// (__syncthreads drain semantics — stable across graph replays).
// LDS XOR-swizzle via pre-swizzled global source (rule #21), 0 bank conflicts.
// XCD-chunked block swizzle (T1, gridDim%8==0 -> bijective).
// OUT_BF16 epilogue: repack C-tile through LDS (reusing the 32KB staging
// buffer after the final barrier) so global stores are 16B fully-coalesced
// (the old path was 64 scalar 2B stores/thread in 32B segments).
template<bool OUT_BF16>
__global__ __launch_bounds__(256, 4)
void gemm_bt(const unsigned short* __restrict__ A,
             const unsigned short* __restrict__ Bt,
             const float* __restrict__ bias,
             void* __restrict__ Cout,
             int Ncols, int K)
{
  __shared__ __align__(16) unsigned char lds[32768];
  unsigned char* lA = lds;            // [128 rows][64 k] bf16 = 16 KiB
  unsigned char* lB = lds + 16384;    // [128 cols][64 k] bf16 = 16 KiB
  const int tid = threadIdx.x;
  const int lane = tid & 63;
  const int wid = tid >> 6;
  const int wr = (wid >> 1) * 64;   // wave row offset in tile
  const int wc = (wid & 1) * 64;    // wave col offset in tile
  const int nbx = Ncols >> 7;
  const int bid = (int)blockIdx.x;
  const int cpx = (int)gridDim.x >> 3;
  const int swz = (bid & 7) * cpx + (bid >> 3);
  const int bx = swz % nbx;
  const int by = swz / nbx;
  const long row0 = (long)by << 7;
  const int col0 = bx << 7;

  f32x4 acc[4][4];
#pragma unroll
  for (int i = 0; i < 4; ++i)
#pragma unroll
    for (int j = 0; j < 4; ++j) acc[i][j] = (f32x4)0.0f;

  for (int kt = 0; kt < K; kt += 64) {
#pragma unroll
    for (int i = 0; i < 4; ++i) {
      const int f = i * 256 + tid;          // 16B chunk index 0..1023
      const int r = f >> 3;                 // tile row 0..127
      const int cd = (f & 7) ^ (r & 7);     // inverse-swizzled source chunk
      gload_lds16(A + (row0 + r) * (long)K + kt + cd * 8, lA + f * 16);
      gload_lds16(Bt + (long)(col0 + r) * K + kt + cd * 8, lB + f * 16);
    }
    __syncthreads();
#pragma unroll
    for (int kk = 0; kk < 2; ++kk) {
      bf16x8 af[4], bfv[4];
#pragma unroll
      for (int fm = 0; fm < 4; ++fm) {
        const int row = wr + fm * 16 + (lane & 15);
        const int ch = (kk * 4 + (lane >> 4)) ^ (row & 7);
        af[fm] = __builtin_bit_cast(bf16x8, *(const u32x4*)(lA + row * 128 + ch * 16));
      }
#pragma unroll
      for (int fn = 0; fn < 4; ++fn) {
        const int row = wc + fn * 16 + (lane & 15);
        const int ch = (kk * 4 + (lane >> 4)) ^ (row & 7);
        bfv[fn] = __builtin_bit_cast(bf16x8, *(const u32x4*)(lB + row * 128 + ch * 16));
      }
#pragma unroll
      for (int fm = 0; fm < 4; ++fm)
#pragma unroll
        for (int fn = 0; fn < 4; ++fn)
          acc[fm][fn] = __builtin_amdgcn_mfma_f32_16x16x32_bf16(af[fm], bfv[fn], acc[fm][fn], 0, 0, 0);
    }
    __syncthreads();
  }

  if constexpr (OUT_BF16) {
    // Stage bf16 C-tile into lds[32KB]: logical [row][col], byte within row
    // rotated by (row*32)&255 to spread ds_write banks (<=4-way, one-time).
#pragma unroll
    for (int fn = 0; fn < 4; ++fn) {
      const int n_loc = wc + fn * 16 + (lane & 15);
      const float bn = bias[col0 + n_loc];
#pragma unroll
      for (int fm = 0; fm < 4; ++fm) {
        const int rb = wr + fm * 16 + ((lane >> 4) << 2);
#pragma unroll
        for (int j = 0; j < 4; ++j) {
          const int row = rb + j;
          *(unsigned short*)(lds + row * 256 + ((n_loc * 2 + row * 32) & 255)) =
              (unsigned short)f2bf(acc[fm][fn][j] + bn);
        }
      }
    }
    __syncthreads();
    // 2048 16B chunks, 8 per thread; consecutive tids -> consecutive 16B in a
    // row (16 chunks/row) -> fully coalesced 16B global stores.
#pragma unroll
    for (int i = 0; i < 8; ++i) {
      const int chunk = i * 256 + tid;
      const int row = chunk >> 4;
      const int co = (chunk & 15) * 16;   // logical byte col
      const u32x4 v = *(const u32x4*)(lds + row * 256 + ((co + row * 32) & 255));
      *(u32x4*)((unsigned short*)Cout + (row0 + row) * (long)Ncols + col0 + (co >> 1)) = v;
    }
  } else {
#pragma unroll
    for (int fn = 0; fn < 4; ++fn) {
      const int n = col0 + wc + fn * 16 + (lane & 15);
      const float bn = bias[n];
#pragma unroll
      for (int fm = 0; fm < 4; ++fm) {
        const long mbase = row0 + wr + fm * 16 + ((lane >> 4) << 2);
#pragma unroll
        for (int j = 0; j < 4; ++j)
          ((float*)Cout)[(mbase + j) * (long)Ncols + n] = acc[fm][fn][j] + bn;
      }
    }
  }
}

// TWO query rows per wave (doubled gather ILP: 14 loads in flight).
// qkv row layout: [q(512) | k(512) | v(512)] bf16; lane l covers dims
// [l*8, l*8+8) == head h=l>>3, d-segment (l&7)*8.
__global__ __launch_bounds__(256)
void nbr_attn(const unsigned short* __restrict__ qkv,
              const int* __restrict__ nbr,
              unsigned short* __restrict__ aout)
{
  const int w = (int)((blockIdx.x * 256 + threadIdx.x) >> 6);
  const int lane = threadIdx.x & 63;
  const int r0 = w * 2;                 // global row pair (same batch: SEQN even)
  const int n0 = r0 & (SEQN - 1);
  const int b  = r0 >> 14;

  const unsigned short* qr = qkv + (size_t)r0 * 1536;
  const u32x4 q0raw = *(const u32x4*)(qr + lane * 8);
  const u32x4 q1raw = *(const u32x4*)(qr + 1536 + lane * 8);

  int t[6];
  t[0] = nbr[n0];            t[3] = nbr[n0 + 1];
  t[1] = nbr[SEQN + n0];     t[4] = nbr[SEQN + n0 + 1];
  t[2] = nbr[2 * SEQN + n0]; t[5] = nbr[2 * SEQN + n0 + 1];

  const unsigned short* base = qkv + (size_t)b * SEQN * 1536 + 512 + lane * 8;
  u32x4 kr[6], vr[6];
#pragma unroll
  for (int k = 0; k < 6; ++k) {
    const unsigned short* p = base + (size_t)(t[k] > 0 ? t[k] : 0) * 1536;
    kr[k] = *(const u32x4*)p;
    vr[k] = *(const u32x4*)(p + 512);
  }

  float qv0[8], qv1[8];
#pragma unroll
  for (int i = 0; i < 4; ++i) {
    qv0[2 * i] = bf2f(q0raw[i] & 0xffffu);
    qv0[2 * i + 1] = bf2f(q0raw[i] >> 16);
    qv1[2 * i] = bf2f(q1raw[i] & 0xffffu);
    qv1[2 * i + 1] = bf2f(q1raw[i] >> 16);
  }

  float s[6];
#pragma unroll
  for (int k = 0; k < 6; ++k) {
    const float* q = (k < 3) ? qv0 : qv1;
    float d = 0.f;
#pragma unroll
    for (int i = 0; i < 4; ++i)
      d += q[2 * i] * bf2f(kr[k][i] & 0xffffu) + q[2 * i + 1] * bf2f(kr[k][i] >> 16);
    d += __shfl_xor(d, 1);
    d += __shfl_xor(d, 2);
    d += __shfl_xor(d, 4);
    s[k] = d * 0.125f;
  }

#pragma unroll
  for (int rrow = 0; rrow < 2; ++rrow) {
    const int o = rrow * 3;
    float m = -3.0e38f;
#pragma unroll
    for (int k = 0; k < 3; ++k)
      if (t[o + k] != -1) m = fmaxf(m, s[o + k]);
    float e[3], sum = 0.f;
#pragma unroll
    for (int k = 0; k < 3; ++k) {
      e[k] = (t[o + k] != -1) ? __expf(s[o + k] - m) : 0.f;
      sum += e[k];
    }
    const float inv = sum > 0.f ? 1.f / sum : 0.f;
    float acc[8] = {0.f, 0.f, 0.f, 0.f, 0.f, 0.f, 0.f, 0.f};
#pragma unroll
    for (int k = 0; k < 3; ++k) {
      const float wgt = e[k] * inv;
#pragma unroll
      for (int i = 0; i < 4; ++i) {
        acc[2 * i] += wgt * bf2f(vr[o + k][i] & 0xffffu);
        acc[2 * i + 1] += wgt * bf2f(vr[o + k][i] >> 16);
      }
    }
    u32x4 ov;
#pragma unroll
    for (int i = 0; i < 4; ++i)
      ov[i] = f2bf(acc[2 * i]) | (f2bf(acc[2 * i + 1]) << 16);
    *(u32x4*)(aout + (size_t)(r0 + rrow) * 512 + lane * 8) = ov;
  }
}

// Fused x f32->bf16 conversion + weight/bias prep (one dispatch).
__global__ __launch_bounds__(256)
void cvt_prep(const float* __restrict__ x, unsigned short* __restrict__ xb,
              const float* __restrict__ Wq, const float* __restrict__ Wk,
              const float* __restrict__ Wv, const float* __restrict__ Wo,
              const float* __restrict__ bq, const float* __restrict__ bk,
              const float* __restrict__ bv,
              unsigned short* __restrict__ wf, unsigned short* __restrict__ wo,
              float* __restrict__ biasf)
{
  const int i = blockIdx.x * 256 + threadIdx.x;
  if (i < 262144) {
    wf[i] = (unsigned short)f2bf(Wq[i]);
    wf[262144 + i] = (unsigned short)f2bf(Wk[i]);
    wf[524288 + i] = (unsigned short)f2bf(Wv[i]);
    wo[i] = (unsigned short)f2bf(Wo[i]);
  }
  if (i < 512) {
    biasf[i] = bq[i];
    biasf[512 + i] = bk[i];
    biasf[1024 + i] = bv[i];
  }
#pragma unroll
  for (int t = i; t < 4194304; t += 1048576) {
    const float4* p = (const float4*)(x + (size_t)t * 8);
    const float4 a = p[0], c = p[1];
    u32x4 o;
    o[0] = f2bf(a.x) | (f2bf(a.y) << 16);
    o[1] = f2bf(a.z) | (f2bf(a.w) << 16);
    o[2] = f2bf(c.x) | (f2bf(c.y) << 16);
    o[3] = f2bf(c.z) | (f2bf(c.w) << 16);
    *(u32x4*)(xb + (size_t)t * 8) = o;
  }
}

extern "C" void kernel_launch(void* const* d_in, const int* in_sizes, int n_in,
                              void* d_out, int out_size, void* d_ws, size_t ws_size,
                              hipStream_t stream) {
  const float* x  = (const float*)d_in[0];
  const int* nbr  = (const int*)d_in[1];
  const float* Wq = (const float*)d_in[2];
  const float* bq = (const float*)d_in[3];
  const float* Wk = (const float*)d_in[4];
  const float* bk = (const float*)d_in[5];
  const float* Wv = (const float*)d_in[6];
  const float* bv = (const float*)d_in[7];
  const float* Wo = (const float*)d_in[8];
  const float* bo = (const float*)d_in[9];
  float* out = (float*)d_out;
  unsigned char* ws = (unsigned char*)d_ws;

  // ws layout (bytes):
  //   [0, 64Mi)            x_bf16, later reused as attn_out_bf16 (65536*512*2)
  //   [64Mi, 256Mi)        qkv bf16 (65536*1536*2 = 192Mi)
  //   [256Mi, +1.5Mi)      fused W (Wq;Wk;Wv) bf16 [1536][512]
  //   [..., +0.5Mi)        Wo bf16 [512][512]
  //   [..., +6Ki)          fused bias f32 [1536]
  unsigned short* xb  = (unsigned short*)(ws);
  unsigned short* qkv = (unsigned short*)(ws + 67108864UL);
  unsigned short* wf  = (unsigned short*)(ws + 268435456UL);
  unsigned short* wo  = (unsigned short*)(ws + 270008320UL);
  float* biasf        = (float*)(ws + 270532608UL);

  cvt_prep<<<4096, 256, 0, stream>>>(x, xb, Wq, Wk, Wv, Wo, bq, bk, bv, wf, wo, biasf);
  // QKV projection: M=65536, N=1536, K=512
  gemm_bt<true><<<dim3(512 * 12), 256, 0, stream>>>(xb, wf, biasf, qkv, 1536, 512);
  // neighbor attention (2 rows/wave; reuses xb region for output)
  nbr_attn<<<8192, 256, 0, stream>>>(qkv, nbr, xb);
  // output projection: M=65536, N=512, K=512, f32 out
  gemm_bt<false><<<dim3(512 * 4), 256, 0, stream>>>(xb, wo, bo, out, 512, 512);
}